// Round 2
// baseline (866.880 us; speedup 1.0000x reference)
//
#include <hip/hip_runtime.h>
#include <hip/hip_bf16.h>

// LightGCN 3-hop GraphConv (M4_86749749444857).
// R7->R8: fine_kernel was top dispatch (109us, 8x redundant bucket reads, 23%
// occupancy). Buckets shrink 512->128 rows (NB=1172): fine is now one block per
// bucket, reads es2 ONCE (staged to LDS obuf while histogramming 128 counters),
// scans, and scatters LDS->global (write frontier 1172x64B, L2-assembled).
// Coarse/bhist/bscan move to 2048-slot bucket tables with a two-level scan.

#define D 64
typedef unsigned short u16;

#define NBP   2048   // padded bucket count (real NB = ceil(n/128) = 1172)
#define BSH   7      // bucket shift: 128 rows/bucket
#define TILE  2048   // edges per coarse block
#define FCAP  4608   // fine LDS slots (mean 4096 + 8 sigma)

__device__ __forceinline__ float bf2f(u16 h) {
    union { unsigned int u; float f; } c;
    c.u = ((unsigned int)h) << 16;
    return c.f;
}
__device__ __forceinline__ u16 f2bf(float f) {
    union { float f; unsigned int u; } c; c.f = f;
    unsigned int r = c.u + 0x7FFFu + ((c.u >> 16) & 1u);  // RNE
    return (u16)(r >> 16);
}

struct U4 { u16 a, b, c, d; } __attribute__((aligned(8)));

// ---------------- dtype sniffing ----------------
__global__ void detect_kernel(const u16* __restrict__ emb,
                              const u16* __restrict__ vals,
                              int* __restrict__ flags) {
    int lane = threadIdx.x;  // 64 threads, 1 block
    int se = 0, sv = 0;
    for (int k = 0; k < 16; ++k) {
        int idx = (lane * 16 + k) * 2;
        u16 he = emb[idx];
        int ee = (he >> 7) & 0xFF;
        if (ee >= 100 && ee < 127) se++;
        u16 hv = vals[idx];
        int ev = (hv >> 7) & 0xFF;
        if ((hv >> 15) == 0 && ev >= 60 && ev < 123) sv++;
    }
    atomicAdd(&flags[0], se);
    atomicAdd(&flags[1], sv);
}

// ---------------- ego -> bf16 X0 ----------------
__global__ __launch_bounds__(256)
void convert_kernel(const void* __restrict__ ue, const void* __restrict__ ie,
                    const int* __restrict__ flags, u16* __restrict__ x0,
                    int total, int usz) {
    int i = (blockIdx.x * blockDim.x + threadIdx.x) * 4;
    if (i >= total) return;
    const void* src = (i < usz) ? ue : ie;
    int off = (i < usz) ? i : i - usz;
    U4 o;
    if (flags[0] >= 512) {
        o = *(const U4*)((const u16*)src + off);
    } else {
        const float4 v = *(const float4*)((const float*)src + off);
        o.a = f2bf(v.x); o.b = f2bf(v.y); o.c = f2bf(v.z); o.d = f2bf(v.w);
    }
    *(U4*)(x0 + i) = o;
}

// ---------------- bucket histogram (LDS-aggregated, 2048 buckets) ----------------
__global__ __launch_bounds__(256)
void bhist_kernel(const int* __restrict__ row, int* __restrict__ bcnt, int nnz) {
    __shared__ int h[NBP];
    int t = threadIdx.x;
#pragma unroll
    for (int j = 0; j < NBP / 256; ++j) h[t + j * 256] = 0;
    __syncthreads();
    for (int i = blockIdx.x * 256 + t; i < nnz; i += gridDim.x * 256)
        atomicAdd(&h[row[i] >> BSH], 1);
    __syncthreads();
#pragma unroll
    for (int j = 0; j < NBP / 256; ++j) {
        int b = t + j * 256;
        if (h[b]) atomicAdd(&bcnt[b], h[b]);
    }
}

// single block, 512 threads, 4 buckets/thread: exclusive scan of bucket counts
__global__ void bscan_kernel(const int* __restrict__ bcnt, int* __restrict__ bbase,
                             int* __restrict__ bcursor, int nb, int nnz) {
    __shared__ int wsum[512];
    int t = threadIdx.x;
    int v[4], l[4];
    int acc = 0;
#pragma unroll
    for (int k = 0; k < 4; ++k) {
        int i = t * 4 + k;
        v[k] = (i < nb) ? bcnt[i] : 0;
        acc += v[k];
        l[k] = acc;
    }
    wsum[t] = acc;
    __syncthreads();
    for (int off = 1; off < 512; off <<= 1) {
        int a = (t >= off) ? wsum[t - off] : 0;
        __syncthreads();
        wsum[t] += a;
        __syncthreads();
    }
    int base = wsum[t] - acc;
#pragma unroll
    for (int k = 0; k < 4; ++k) {
        int i = t * 4 + k;
        int excl = base + l[k] - v[k];
        bbase[i] = excl;
        bcursor[i] = excl;
    }
    if (t == 0) bbase[nb] = nnz;
}

// ---------------- coarse sort: COO -> bucket-grouped es2 ----------------
// es2 entry: .x = (row&127)<<18 | col   .y = val bits
__global__ __launch_bounds__(256)
void coarse_kernel(const int* __restrict__ row, const int* __restrict__ col,
                   const void* __restrict__ vals, const int* __restrict__ flags,
                   int* __restrict__ bcursor, int2* __restrict__ es2, int nnz) {
    __shared__ int2 ebuf[TILE];
    __shared__ u16  slotb[TILE];
    __shared__ int  hcnt[NBP], hscn[NBP];
    __shared__ int  wsum[256];
    int t = threadIdx.x;
    int base = blockIdx.x * TILE;
    int tcnt = nnz - base; if (tcnt > TILE) tcnt = TILE;
    bool vbf = (flags[1] >= 512);

#pragma unroll
    for (int j = 0; j < NBP / 256; ++j) hcnt[t + j * 256] = 0;
    __syncthreads();

    int eb[8], er[8], ep[8], ev[8];
#pragma unroll
    for (int k = 0; k < 8; ++k) {
        int i = base + k * 256 + t;
        eb[k] = -1;
        if (k * 256 + t < tcnt) {
            int r = row[i];
            int c = col[i];
            float v = vbf ? bf2f(((const u16*)vals)[i]) : ((const float*)vals)[i];
            eb[k] = r >> BSH;
            ep[k] = ((r & 127) << 18) | c;
            ev[k] = __float_as_int(v);
            er[k] = atomicAdd(&hcnt[eb[k]], 1);
        }
    }
    __syncthreads();
    // two-level inclusive scan over 2048 buckets: 8 contiguous slots/thread
    int a = 0, lo[8];
#pragma unroll
    for (int k = 0; k < 8; ++k) {
        a += hcnt[t * 8 + k];
        lo[k] = a;
    }
    wsum[t] = a;
    __syncthreads();
    for (int off = 1; off < 256; off <<= 1) {
        int x = (t >= off) ? wsum[t - off] : 0;
        __syncthreads();
        wsum[t] += x;
        __syncthreads();
    }
    int tp = wsum[t] - a;
#pragma unroll
    for (int k = 0; k < 8; ++k) hscn[t * 8 + k] = tp + lo[k];
    __syncthreads();
    // stage edges bucket-grouped in LDS
#pragma unroll
    for (int k = 0; k < 8; ++k) {
        if (eb[k] >= 0) {
            int slot = hscn[eb[k]] - hcnt[eb[k]] + er[k];
            ebuf[slot] = make_int2(ep[k], ev[k]);
            slotb[slot] = (u16)eb[k];
        }
    }
    __syncthreads();
    // fetch global cursors; fold (goff - tile_start) into hcnt as adj
#pragma unroll
    for (int k = 0; k < 8; ++k) {
        int b = t * 8 + k;
        int c = hcnt[b];
        if (c > 0) {
            int g = atomicAdd(&bcursor[b], c);
            hcnt[b] = g - (hscn[b] - c);
        }
    }
    __syncthreads();
#pragma unroll
    for (int k = 0; k < 8; ++k) {
        int p = k * 256 + t;
        if (p < tcnt) {
            int b = slotb[p];
            es2[hcnt[b] + p] = ebuf[p];
        }
    }
}

// ---------------- fine sort + rp emit: one block per 128-row bucket ----------
// Single global read: stage bucket edges raw into obuf while histogramming,
// scan 128 counters, scatter LDS->global es (writes L2-assembled per bucket).
__global__ __launch_bounds__(256)
void fine_kernel(const int2* __restrict__ es2, const int* __restrict__ bbase,
                 int2* __restrict__ es, int* __restrict__ rp, int n, int nnz) {
    __shared__ int2 obuf[FCAP];
    __shared__ int hist[128], scn[128], cur[128];
    int b = blockIdx.x, t = threadIdx.x;
    int r0 = b << BSH;
    int s = bbase[b], e = bbase[b + 1];
    int cnt = e - s;
    if (b == 0 && t == 0) rp[n] = nnz;

    if (t < 128) hist[t] = 0;
    __syncthreads();
    bool fit = (cnt <= FCAP);
    if (fit) {
        for (int i = s + t; i < e; i += 256) {
            int2 p = es2[i];
            obuf[i - s] = p;
            atomicAdd(&hist[(unsigned)p.x >> 18], 1);
        }
    } else {
        for (int i = s + t; i < e; i += 256)
            atomicAdd(&hist[(unsigned)es2[i].x >> 18], 1);
    }
    __syncthreads();
    if (t < 128) scn[t] = hist[t];
    __syncthreads();
    for (int off = 1; off < 128; off <<= 1) {
        int a = (t < 128 && t >= off) ? scn[t - off] : 0;
        __syncthreads();
        if (t < 128) scn[t] += a;
        __syncthreads();
    }
    if (t < 128) {
        int ex = scn[t] - hist[t];
        int r = r0 + t;
        if (r < n) rp[r] = s + ex;
        cur[t] = s + ex;  // global destination cursor
    }
    __syncthreads();

    if (fit) {
        for (int p = t; p < cnt; p += 256) {
            int2 v = obuf[p];
            int rl = (unsigned)v.x >> 18;
            int pos = atomicAdd(&cur[rl], 1);
            es[pos] = make_int2(v.x & 0x3FFFF, v.y);
        }
    } else {
        // statistically-unreachable overflow: second global read
        for (int i = s + t; i < e; i += 256) {
            int2 v = es2[i];
            int rl = (unsigned)v.x >> 18;
            int pos = atomicAdd(&cur[rl], 1);
            es[pos] = make_int2(v.x & 0x3FFFF, v.y);
        }
    }
}

// ---------------- SpMM: 4 rows/wave, 16 lanes/row, ushort4 gather ----------------
// Lane l: quarter qt = l>>4 owns row (wid*4 + qt); sub = l&15 owns dims 4*sub..4*sub+3.

__global__ __launch_bounds__(256)
void spmm_kernel(const u16* __restrict__ x, u16* __restrict__ y,
                 const int* __restrict__ rp, const int2* __restrict__ es, int n) {
    int wid  = (blockIdx.x * blockDim.x + threadIdx.x) >> 6;
    int lane = threadIdx.x & 63;
    int qt   = lane >> 4;
    int sub  = lane & 15;
    int r    = (wid << 2) + qt;
    int e = 0, e1 = 0;
    if (r < n) { e = rp[r]; e1 = rp[r + 1]; }
    const u16* xs = x + (sub << 2);

    float a0 = 0.f, a1 = 0.f, a2 = 0.f, a3 = 0.f;
    float b0 = 0.f, b1 = 0.f, b2 = 0.f, b3 = 0.f;

    for (; e + 8 <= e1; e += 8) {
        int2 p0 = es[e],     p1 = es[e + 1], p2 = es[e + 2], p3 = es[e + 3];
        int2 p4 = es[e + 4], p5 = es[e + 5], p6 = es[e + 6], p7 = es[e + 7];
        U4 v0 = *(const U4*)(xs + (p0.x << 6));
        U4 v1 = *(const U4*)(xs + (p1.x << 6));
        U4 v2 = *(const U4*)(xs + (p2.x << 6));
        U4 v3 = *(const U4*)(xs + (p3.x << 6));
        U4 v4 = *(const U4*)(xs + (p4.x << 6));
        U4 v5 = *(const U4*)(xs + (p5.x << 6));
        U4 v6 = *(const U4*)(xs + (p6.x << 6));
        U4 v7 = *(const U4*)(xs + (p7.x << 6));
        float w0 = __int_as_float(p0.y), w1 = __int_as_float(p1.y);
        float w2 = __int_as_float(p2.y), w3 = __int_as_float(p3.y);
        float w4 = __int_as_float(p4.y), w5 = __int_as_float(p5.y);
        float w6 = __int_as_float(p6.y), w7 = __int_as_float(p7.y);
        a0 += w0 * bf2f(v0.a); a1 += w0 * bf2f(v0.b); a2 += w0 * bf2f(v0.c); a3 += w0 * bf2f(v0.d);
        b0 += w1 * bf2f(v1.a); b1 += w1 * bf2f(v1.b); b2 += w1 * bf2f(v1.c); b3 += w1 * bf2f(v1.d);
        a0 += w2 * bf2f(v2.a); a1 += w2 * bf2f(v2.b); a2 += w2 * bf2f(v2.c); a3 += w2 * bf2f(v2.d);
        b0 += w3 * bf2f(v3.a); b1 += w3 * bf2f(v3.b); b2 += w3 * bf2f(v3.c); b3 += w3 * bf2f(v3.d);
        a0 += w4 * bf2f(v4.a); a1 += w4 * bf2f(v4.b); a2 += w4 * bf2f(v4.c); a3 += w4 * bf2f(v4.d);
        b0 += w5 * bf2f(v5.a); b1 += w5 * bf2f(v5.b); b2 += w5 * bf2f(v5.c); b3 += w5 * bf2f(v5.d);
        a0 += w6 * bf2f(v6.a); a1 += w6 * bf2f(v6.b); a2 += w6 * bf2f(v6.c); a3 += w6 * bf2f(v6.d);
        b0 += w7 * bf2f(v7.a); b1 += w7 * bf2f(v7.b); b2 += w7 * bf2f(v7.c); b3 += w7 * bf2f(v7.d);
    }
    for (; e < e1; ++e) {
        int2 p = es[e];
        U4 v = *(const U4*)(xs + (p.x << 6));
        float w = __int_as_float(p.y);
        a0 += w * bf2f(v.a); a1 += w * bf2f(v.b); a2 += w * bf2f(v.c); a3 += w * bf2f(v.d);
    }
    if (r < n) {
        U4 o;
        o.a = f2bf(a0 + b0); o.b = f2bf(a1 + b1);
        o.c = f2bf(a2 + b2); o.d = f2bf(a3 + b3);
        *(U4*)(y + (r << 6) + (sub << 2)) = o;
    }
}

__global__ __launch_bounds__(256)
void spmm_last_kernel(const u16* __restrict__ x2, const u16* __restrict__ x1,
                      float* __restrict__ out,
                      const int* __restrict__ rp, const int2* __restrict__ es, int n) {
    int wid  = (blockIdx.x * blockDim.x + threadIdx.x) >> 6;
    int lane = threadIdx.x & 63;
    int qt   = lane >> 4;
    int sub  = lane & 15;
    int r    = (wid << 2) + qt;
    int e = 0, e1 = 0;
    if (r < n) { e = rp[r]; e1 = rp[r + 1]; }
    const u16* xs = x2 + (sub << 2);

    float a0 = 0.f, a1 = 0.f, a2 = 0.f, a3 = 0.f;
    float b0 = 0.f, b1 = 0.f, b2 = 0.f, b3 = 0.f;

    for (; e + 8 <= e1; e += 8) {
        int2 p0 = es[e],     p1 = es[e + 1], p2 = es[e + 2], p3 = es[e + 3];
        int2 p4 = es[e + 4], p5 = es[e + 5], p6 = es[e + 6], p7 = es[e + 7];
        U4 v0 = *(const U4*)(xs + (p0.x << 6));
        U4 v1 = *(const U4*)(xs + (p1.x << 6));
        U4 v2 = *(const U4*)(xs + (p2.x << 6));
        U4 v3 = *(const U4*)(xs + (p3.x << 6));
        U4 v4 = *(const U4*)(xs + (p4.x << 6));
        U4 v5 = *(const U4*)(xs + (p5.x << 6));
        U4 v6 = *(const U4*)(xs + (p6.x << 6));
        U4 v7 = *(const U4*)(xs + (p7.x << 6));
        float w0 = __int_as_float(p0.y), w1 = __int_as_float(p1.y);
        float w2 = __int_as_float(p2.y), w3 = __int_as_float(p3.y);
        float w4 = __int_as_float(p4.y), w5 = __int_as_float(p5.y);
        float w6 = __int_as_float(p6.y), w7 = __int_as_float(p7.y);
        a0 += w0 * bf2f(v0.a); a1 += w0 * bf2f(v0.b); a2 += w0 * bf2f(v0.c); a3 += w0 * bf2f(v0.d);
        b0 += w1 * bf2f(v1.a); b1 += w1 * bf2f(v1.b); b2 += w1 * bf2f(v1.c); b3 += w1 * bf2f(v1.d);
        a0 += w2 * bf2f(v2.a); a1 += w2 * bf2f(v2.b); a2 += w2 * bf2f(v2.c); a3 += w2 * bf2f(v2.d);
        b0 += w3 * bf2f(v3.a); b1 += w3 * bf2f(v3.b); b2 += w3 * bf2f(v3.c); b3 += w3 * bf2f(v3.d);
        a0 += w4 * bf2f(v4.a); a1 += w4 * bf2f(v4.b); a2 += w4 * bf2f(v4.c); a3 += w4 * bf2f(v4.d);
        b0 += w5 * bf2f(v5.a); b1 += w5 * bf2f(v5.b); b2 += w5 * bf2f(v5.c); b3 += w5 * bf2f(v5.d);
        a0 += w6 * bf2f(v6.a); a1 += w6 * bf2f(v6.b); a2 += w6 * bf2f(v6.c); a3 += w6 * bf2f(v6.d);
        b0 += w7 * bf2f(v7.a); b1 += w7 * bf2f(v7.b); b2 += w7 * bf2f(v7.c); b3 += w7 * bf2f(v7.d);
    }
    for (; e < e1; ++e) {
        int2 p = es[e];
        U4 v = *(const U4*)(xs + (p.x << 6));
        float w = __int_as_float(p.y);
        a0 += w * bf2f(v.a); a1 += w * bf2f(v.b); a2 += w * bf2f(v.c); a3 += w * bf2f(v.d);
    }
    if (r < n) {
        int idx = (r << 6) + (sub << 2);
        U4 h1v = *(const U4*)(x1 + idx);
        U4 h2v = *(const U4*)(x2 + idx);
        float h1a = bf2f(h1v.a), h1b = bf2f(h1v.b), h1c = bf2f(h1v.c), h1d = bf2f(h1v.d);
        float h2a = bf2f(h2v.a), h2b = bf2f(h2v.b), h2c = bf2f(h2v.c), h2d = bf2f(h2v.d);
        float4 o;
        o.x = (h1a + h2a + (a0 + b0)) * (1.0f / 3.0f);
        o.y = (h1b + h2b + (a1 + b1)) * (1.0f / 3.0f);
        o.z = (h1c + h2c + (a2 + b2)) * (1.0f / 3.0f);
        o.w = (h1d + h2d + (a3 + b3)) * (1.0f / 3.0f);
        *(float4*)(out + idx) = o;
        float4 l;
        l.x = h1a; l.y = h1b; l.z = h1c; l.w = h1d;
        *(float4*)(out + (size_t)n * D + idx) = l;
    }
}

// ---------------- launch ----------------

extern "C" void kernel_launch(void* const* d_in, const int* in_sizes, int n_in,
                              void* d_out, int out_size, void* d_ws, size_t ws_size,
                              hipStream_t stream) {
    const void* ue   = d_in[0];
    const void* ie   = d_in[1];
    const int*  row  = (const int*)d_in[2];
    const int*  col  = (const int*)d_in[3];
    const void* vals = d_in[4];

    const int nu  = in_sizes[0] / D;   // 100000
    const int ni  = in_sizes[1] / D;   //  50000
    const int n   = nu + ni;           // 150000
    const int nnz = in_sizes[2];       // 4800000

    // workspace (~97 MB). es2 aliases X1+X2 (dead before spmm writes X1).
    char* ws = (char*)d_ws;
    u16*  X0     = (u16*)ws;   ws += (size_t)n * D * sizeof(u16);
    u16*  X1     = (u16*)ws;   ws += (size_t)n * D * sizeof(u16);
    u16*  X2     = (u16*)ws;   ws += (size_t)n * D * sizeof(u16);
    int2* es2    = (int2*)X1;  // nnz*8B == 2*n*D*2B exactly
    int2* es     = (int2*)ws;  ws += (size_t)nnz * sizeof(int2);
    int*  rp     = (int*)ws;   ws += (size_t)(n + 1) * sizeof(int);
    int*  bcnt   = (int*)ws;   ws += NBP * sizeof(int);
    int*  flags  = (int*)ws;   ws += 2 * sizeof(int);
    int*  bbase  = (int*)ws;   ws += (NBP + 1) * sizeof(int);
    int*  bcursor= (int*)ws;   ws += NBP * sizeof(int);

    const int tb = 256;
    const int rblocks = (n + 15) / 16;             // 4 rows/wave, 4 waves/block
    const int cblocks = (n * D / 4 + tb - 1) / tb;
    const int NB      = (n + 127) / 128;            // 1172
    const int coarseb = (nnz + TILE - 1) / TILE;    // 2344

    // zero bcnt + flags (contiguous)
    hipMemsetAsync(bcnt, 0, (NBP + 2) * sizeof(int), stream);
    detect_kernel <<<1, 64, 0, stream>>>((const u16*)ue, (const u16*)vals, flags);
    convert_kernel<<<cblocks, tb, 0, stream>>>(ue, ie, flags, X0, n * D, nu * D);
    bhist_kernel  <<<512, tb, 0, stream>>>(row, bcnt, nnz);
    bscan_kernel  <<<1, 512, 0, stream>>>(bcnt, bbase, bcursor, NB, nnz);
    coarse_kernel <<<coarseb, tb, 0, stream>>>(row, col, vals, flags, bcursor, es2, nnz);
    fine_kernel   <<<NB, tb, 0, stream>>>(es2, bbase, es, rp, n, nnz);

    spmm_kernel     <<<rblocks, tb, 0, stream>>>(X0, X1, rp, es, n);
    spmm_kernel     <<<rblocks, tb, 0, stream>>>(X1, X2, rp, es, n);
    spmm_last_kernel<<<rblocks, tb, 0, stream>>>(X2, X1, (float*)d_out, rp, es, n);
}

// Round 3
// 609.418 us; speedup vs baseline: 1.4225x; 1.4225x over previous
//
#include <hip/hip_runtime.h>
#include <hip/hip_bf16.h>

// LightGCN 3-hop GraphConv (M4_86749749444857).
// R8->R9: R8's 128-row buckets collapsed coarse (write runs ~1.75 edges -> 151MB
// sector-RMW writes, 397us). Revert sort to 512-row buckets (runs ~7 edges,
// coalesced, R1-proven ~100us). fine becomes one 512-thread block per bucket:
// 1 HBM hist pass + 4 L2-hot chunk passes, LDS-scatter into obuf at sorted
// positions, then stream obuf->es as full coalesced lines (no scattered HBM
// writes anywhere in the pipeline).

#define D 64
typedef unsigned short u16;

#define NBP   512    // padded bucket count (real NB = ceil(n/512) = 293)
#define BSH   9      // 512 rows/bucket
#define TILE  2048   // edges per coarse block
#define FCAP  4608   // fine LDS chunk slots (128 rows x 32 mean = 4096 + 8 sigma)

__device__ __forceinline__ float bf2f(u16 h) {
    union { unsigned int u; float f; } c;
    c.u = ((unsigned int)h) << 16;
    return c.f;
}
__device__ __forceinline__ u16 f2bf(float f) {
    union { float f; unsigned int u; } c; c.f = f;
    unsigned int r = c.u + 0x7FFFu + ((c.u >> 16) & 1u);  // RNE
    return (u16)(r >> 16);
}

struct U4 { u16 a, b, c, d; } __attribute__((aligned(8)));

// ---------------- dtype sniffing ----------------
__global__ void detect_kernel(const u16* __restrict__ emb,
                              const u16* __restrict__ vals,
                              int* __restrict__ flags) {
    int lane = threadIdx.x;  // 64 threads, 1 block
    int se = 0, sv = 0;
    for (int k = 0; k < 16; ++k) {
        int idx = (lane * 16 + k) * 2;
        u16 he = emb[idx];
        int ee = (he >> 7) & 0xFF;
        if (ee >= 100 && ee < 127) se++;
        u16 hv = vals[idx];
        int ev = (hv >> 7) & 0xFF;
        if ((hv >> 15) == 0 && ev >= 60 && ev < 123) sv++;
    }
    atomicAdd(&flags[0], se);
    atomicAdd(&flags[1], sv);
}

// ---------------- ego -> bf16 X0 ----------------
__global__ __launch_bounds__(256)
void convert_kernel(const void* __restrict__ ue, const void* __restrict__ ie,
                    const int* __restrict__ flags, u16* __restrict__ x0,
                    int total, int usz) {
    int i = (blockIdx.x * blockDim.x + threadIdx.x) * 4;
    if (i >= total) return;
    const void* src = (i < usz) ? ue : ie;
    int off = (i < usz) ? i : i - usz;
    U4 o;
    if (flags[0] >= 512) {
        o = *(const U4*)((const u16*)src + off);
    } else {
        const float4 v = *(const float4*)((const float*)src + off);
        o.a = f2bf(v.x); o.b = f2bf(v.y); o.c = f2bf(v.z); o.d = f2bf(v.w);
    }
    *(U4*)(x0 + i) = o;
}

// ---------------- bucket histogram (LDS-aggregated) ----------------
__global__ __launch_bounds__(256)
void bhist_kernel(const int* __restrict__ row, int* __restrict__ bcnt, int nnz) {
    __shared__ int h[NBP];
    int t = threadIdx.x;
    h[t] = 0; h[t + 256] = 0;
    __syncthreads();
    for (int i = blockIdx.x * 256 + t; i < nnz; i += gridDim.x * 256)
        atomicAdd(&h[row[i] >> BSH], 1);
    __syncthreads();
    if (h[t])       atomicAdd(&bcnt[t],       h[t]);
    if (h[t + 256]) atomicAdd(&bcnt[t + 256], h[t + 256]);
}

// single block, 512 threads: exclusive scan of bucket counts
__global__ void bscan_kernel(const int* __restrict__ bcnt, int* __restrict__ bbase,
                             int* __restrict__ bcursor, int nb, int nnz) {
    __shared__ int buf[NBP];
    int t = threadIdx.x;
    int v = (t < nb) ? bcnt[t] : 0;
    buf[t] = v;
    __syncthreads();
    for (int off = 1; off < NBP; off <<= 1) {
        int y = (t >= off) ? buf[t - off] : 0;
        __syncthreads();
        buf[t] += y;
        __syncthreads();
    }
    int excl = buf[t] - v;
    bbase[t] = excl;
    bcursor[t] = excl;
    if (t == 0) bbase[nb] = nnz;
}

// ---------------- coarse sort: COO -> bucket-grouped es2 ----------------
// es2 entry: .x = (row&511)<<18 | col   .y = val bits
__global__ __launch_bounds__(256)
void coarse_kernel(const int* __restrict__ row, const int* __restrict__ col,
                   const void* __restrict__ vals, const int* __restrict__ flags,
                   int* __restrict__ bcursor, int2* __restrict__ es2, int nnz) {
    __shared__ int2 ebuf[TILE];
    __shared__ u16  slotb[TILE];
    __shared__ int  hcnt[NBP], hscn[NBP], goff[NBP];
    int t = threadIdx.x;
    int base = blockIdx.x * TILE;
    int tcnt = nnz - base; if (tcnt > TILE) tcnt = TILE;
    bool vbf = (flags[1] >= 512);

    hcnt[t] = 0; hcnt[t + 256] = 0;
    __syncthreads();

    int eb[8], er[8], ep[8], ev[8];
#pragma unroll
    for (int k = 0; k < 8; ++k) {
        int i = base + k * 256 + t;
        eb[k] = -1;
        if (k * 256 + t < tcnt) {
            int r = row[i];
            int c = col[i];
            float v = vbf ? bf2f(((const u16*)vals)[i]) : ((const float*)vals)[i];
            eb[k] = r >> BSH;
            ep[k] = ((r & 511) << 18) | c;
            ev[k] = __float_as_int(v);
            er[k] = atomicAdd(&hcnt[eb[k]], 1);
        }
    }
    __syncthreads();
    hscn[t] = hcnt[t]; hscn[t + 256] = hcnt[t + 256];
    __syncthreads();
    for (int off = 1; off < NBP; off <<= 1) {
        int a0 = (t >= off) ? hscn[t - off] : 0;
        int a1 = (t + 256 >= off) ? hscn[t + 256 - off] : 0;
        __syncthreads();
        hscn[t] += a0; hscn[t + 256] += a1;
        __syncthreads();
    }
#pragma unroll
    for (int k = 0; k < 8; ++k) {
        if (eb[k] >= 0) {
            int slot = hscn[eb[k]] - hcnt[eb[k]] + er[k];
            ebuf[slot] = make_int2(ep[k], ev[k]);
            slotb[slot] = (u16)eb[k];
        }
    }
    __syncthreads();
    if (hcnt[t] > 0)       goff[t]       = atomicAdd(&bcursor[t],       hcnt[t]);
    if (hcnt[t + 256] > 0) goff[t + 256] = atomicAdd(&bcursor[t + 256], hcnt[t + 256]);
    __syncthreads();
#pragma unroll
    for (int k = 0; k < 8; ++k) {
        int p = k * 256 + t;
        if (p < tcnt) {
            int b = slotb[p];
            int dest = goff[b] + (p - (hscn[b] - hcnt[b]));
            es2[dest] = ebuf[p];
        }
    }
}

// ---------------- fine sort + rp emit: 1 block / 512-row bucket, 4 chunks ----
// Pass 1 (HBM): hist[512]. Scan once. Then per 128-row chunk: re-scan bucket
// (L2-hot), LDS-scatter chunk edges into obuf at sorted positions, stream
// obuf -> es coalesced. No scattered global writes.
__global__ __launch_bounds__(512)
void fine_kernel(const int2* __restrict__ es2, const int* __restrict__ bbase,
                 int2* __restrict__ es, int* __restrict__ rp, int n, int nnz) {
    __shared__ int2 obuf[FCAP];
    __shared__ int hist[512], scn[512], cur[128];
    int b = blockIdx.x, t = threadIdx.x;  // 512 threads
    int r0 = b << BSH;
    int s = bbase[b], e = bbase[b + 1];
    if (b == 0 && t == 0) rp[n] = nnz;

    hist[t] = 0;
    __syncthreads();
    for (int i = s + t; i < e; i += 512)
        atomicAdd(&hist[(unsigned)es2[i].x >> 18], 1);
    __syncthreads();
    scn[t] = hist[t];
    __syncthreads();
    for (int off = 1; off < 512; off <<= 1) {
        int a = (t >= off) ? scn[t - off] : 0;
        __syncthreads();
        scn[t] += a;
        __syncthreads();
    }
    {
        int ex = scn[t] - hist[t];
        int r = r0 + t;
        if (r < n) rp[r] = s + ex;
    }

    for (int c = 0; c < 4; ++c) {
        int qb = c * 128;
        int q0 = qb ? scn[qb - 1] : 0;           // excl prefix at chunk start
        int qcnt = scn[qb + 127] - q0;
        int ds = s + q0;
        bool fit = (qcnt <= FCAP);
        if (t < 128) {
            int ex = scn[qb + t] - hist[qb + t];
            cur[t] = fit ? (ex - q0) : (s + ex);  // LDS slot vs global dest
        }
        __syncthreads();
        if (fit) {
            for (int i = s + t; i < e; i += 512) {
                int2 p = es2[i];
                int rl = (unsigned)p.x >> 18;
                if ((rl >> 7) == c) {
                    int pos = atomicAdd(&cur[rl & 127], 1);
                    obuf[pos] = make_int2(p.x & 0x3FFFF, p.y);
                }
            }
            __syncthreads();
            for (int p2 = t; p2 < qcnt; p2 += 512)
                es[ds + p2] = obuf[p2];
            __syncthreads();
        } else {
            // statistically-unreachable overflow: direct global scatter
            for (int i = s + t; i < e; i += 512) {
                int2 p = es2[i];
                int rl = (unsigned)p.x >> 18;
                if ((rl >> 7) == c) {
                    int pos = atomicAdd(&cur[rl & 127], 1);
                    es[pos] = make_int2(p.x & 0x3FFFF, p.y);
                }
            }
            __syncthreads();
        }
    }
}

// ---------------- SpMM: 4 rows/wave, 16 lanes/row, ushort4 gather ----------------
// Lane l: quarter qt = l>>4 owns row (wid*4 + qt); sub = l&15 owns dims 4*sub..4*sub+3.

__global__ __launch_bounds__(256)
void spmm_kernel(const u16* __restrict__ x, u16* __restrict__ y,
                 const int* __restrict__ rp, const int2* __restrict__ es, int n) {
    int wid  = (blockIdx.x * blockDim.x + threadIdx.x) >> 6;
    int lane = threadIdx.x & 63;
    int qt   = lane >> 4;
    int sub  = lane & 15;
    int r    = (wid << 2) + qt;
    int e = 0, e1 = 0;
    if (r < n) { e = rp[r]; e1 = rp[r + 1]; }
    const u16* xs = x + (sub << 2);

    float a0 = 0.f, a1 = 0.f, a2 = 0.f, a3 = 0.f;
    float b0 = 0.f, b1 = 0.f, b2 = 0.f, b3 = 0.f;

    for (; e + 8 <= e1; e += 8) {
        int2 p0 = es[e],     p1 = es[e + 1], p2 = es[e + 2], p3 = es[e + 3];
        int2 p4 = es[e + 4], p5 = es[e + 5], p6 = es[e + 6], p7 = es[e + 7];
        U4 v0 = *(const U4*)(xs + (p0.x << 6));
        U4 v1 = *(const U4*)(xs + (p1.x << 6));
        U4 v2 = *(const U4*)(xs + (p2.x << 6));
        U4 v3 = *(const U4*)(xs + (p3.x << 6));
        U4 v4 = *(const U4*)(xs + (p4.x << 6));
        U4 v5 = *(const U4*)(xs + (p5.x << 6));
        U4 v6 = *(const U4*)(xs + (p6.x << 6));
        U4 v7 = *(const U4*)(xs + (p7.x << 6));
        float w0 = __int_as_float(p0.y), w1 = __int_as_float(p1.y);
        float w2 = __int_as_float(p2.y), w3 = __int_as_float(p3.y);
        float w4 = __int_as_float(p4.y), w5 = __int_as_float(p5.y);
        float w6 = __int_as_float(p6.y), w7 = __int_as_float(p7.y);
        a0 += w0 * bf2f(v0.a); a1 += w0 * bf2f(v0.b); a2 += w0 * bf2f(v0.c); a3 += w0 * bf2f(v0.d);
        b0 += w1 * bf2f(v1.a); b1 += w1 * bf2f(v1.b); b2 += w1 * bf2f(v1.c); b3 += w1 * bf2f(v1.d);
        a0 += w2 * bf2f(v2.a); a1 += w2 * bf2f(v2.b); a2 += w2 * bf2f(v2.c); a3 += w2 * bf2f(v2.d);
        b0 += w3 * bf2f(v3.a); b1 += w3 * bf2f(v3.b); b2 += w3 * bf2f(v3.c); b3 += w3 * bf2f(v3.d);
        a0 += w4 * bf2f(v4.a); a1 += w4 * bf2f(v4.b); a2 += w4 * bf2f(v4.c); a3 += w4 * bf2f(v4.d);
        b0 += w5 * bf2f(v5.a); b1 += w5 * bf2f(v5.b); b2 += w5 * bf2f(v5.c); b3 += w5 * bf2f(v5.d);
        a0 += w6 * bf2f(v6.a); a1 += w6 * bf2f(v6.b); a2 += w6 * bf2f(v6.c); a3 += w6 * bf2f(v6.d);
        b0 += w7 * bf2f(v7.a); b1 += w7 * bf2f(v7.b); b2 += w7 * bf2f(v7.c); b3 += w7 * bf2f(v7.d);
    }
    for (; e < e1; ++e) {
        int2 p = es[e];
        U4 v = *(const U4*)(xs + (p.x << 6));
        float w = __int_as_float(p.y);
        a0 += w * bf2f(v.a); a1 += w * bf2f(v.b); a2 += w * bf2f(v.c); a3 += w * bf2f(v.d);
    }
    if (r < n) {
        U4 o;
        o.a = f2bf(a0 + b0); o.b = f2bf(a1 + b1);
        o.c = f2bf(a2 + b2); o.d = f2bf(a3 + b3);
        *(U4*)(y + (r << 6) + (sub << 2)) = o;
    }
}

__global__ __launch_bounds__(256)
void spmm_last_kernel(const u16* __restrict__ x2, const u16* __restrict__ x1,
                      float* __restrict__ out,
                      const int* __restrict__ rp, const int2* __restrict__ es, int n) {
    int wid  = (blockIdx.x * blockDim.x + threadIdx.x) >> 6;
    int lane = threadIdx.x & 63;
    int qt   = lane >> 4;
    int sub  = lane & 15;
    int r    = (wid << 2) + qt;
    int e = 0, e1 = 0;
    if (r < n) { e = rp[r]; e1 = rp[r + 1]; }
    const u16* xs = x2 + (sub << 2);

    float a0 = 0.f, a1 = 0.f, a2 = 0.f, a3 = 0.f;
    float b0 = 0.f, b1 = 0.f, b2 = 0.f, b3 = 0.f;

    for (; e + 8 <= e1; e += 8) {
        int2 p0 = es[e],     p1 = es[e + 1], p2 = es[e + 2], p3 = es[e + 3];
        int2 p4 = es[e + 4], p5 = es[e + 5], p6 = es[e + 6], p7 = es[e + 7];
        U4 v0 = *(const U4*)(xs + (p0.x << 6));
        U4 v1 = *(const U4*)(xs + (p1.x << 6));
        U4 v2 = *(const U4*)(xs + (p2.x << 6));
        U4 v3 = *(const U4*)(xs + (p3.x << 6));
        U4 v4 = *(const U4*)(xs + (p4.x << 6));
        U4 v5 = *(const U4*)(xs + (p5.x << 6));
        U4 v6 = *(const U4*)(xs + (p6.x << 6));
        U4 v7 = *(const U4*)(xs + (p7.x << 6));
        float w0 = __int_as_float(p0.y), w1 = __int_as_float(p1.y);
        float w2 = __int_as_float(p2.y), w3 = __int_as_float(p3.y);
        float w4 = __int_as_float(p4.y), w5 = __int_as_float(p5.y);
        float w6 = __int_as_float(p6.y), w7 = __int_as_float(p7.y);
        a0 += w0 * bf2f(v0.a); a1 += w0 * bf2f(v0.b); a2 += w0 * bf2f(v0.c); a3 += w0 * bf2f(v0.d);
        b0 += w1 * bf2f(v1.a); b1 += w1 * bf2f(v1.b); b2 += w1 * bf2f(v1.c); b3 += w1 * bf2f(v1.d);
        a0 += w2 * bf2f(v2.a); a1 += w2 * bf2f(v2.b); a2 += w2 * bf2f(v2.c); a3 += w2 * bf2f(v2.d);
        b0 += w3 * bf2f(v3.a); b1 += w3 * bf2f(v3.b); b2 += w3 * bf2f(v3.c); b3 += w3 * bf2f(v3.d);
        a0 += w4 * bf2f(v4.a); a1 += w4 * bf2f(v4.b); a2 += w4 * bf2f(v4.c); a3 += w4 * bf2f(v4.d);
        b0 += w5 * bf2f(v5.a); b1 += w5 * bf2f(v5.b); b2 += w5 * bf2f(v5.c); b3 += w5 * bf2f(v5.d);
        a0 += w6 * bf2f(v6.a); a1 += w6 * bf2f(v6.b); a2 += w6 * bf2f(v6.c); a3 += w6 * bf2f(v6.d);
        b0 += w7 * bf2f(v7.a); b1 += w7 * bf2f(v7.b); b2 += w7 * bf2f(v7.c); b3 += w7 * bf2f(v7.d);
    }
    for (; e < e1; ++e) {
        int2 p = es[e];
        U4 v = *(const U4*)(xs + (p.x << 6));
        float w = __int_as_float(p.y);
        a0 += w * bf2f(v.a); a1 += w * bf2f(v.b); a2 += w * bf2f(v.c); a3 += w * bf2f(v.d);
    }
    if (r < n) {
        int idx = (r << 6) + (sub << 2);
        U4 h1v = *(const U4*)(x1 + idx);
        U4 h2v = *(const U4*)(x2 + idx);
        float h1a = bf2f(h1v.a), h1b = bf2f(h1v.b), h1c = bf2f(h1v.c), h1d = bf2f(h1v.d);
        float h2a = bf2f(h2v.a), h2b = bf2f(h2v.b), h2c = bf2f(h2v.c), h2d = bf2f(h2v.d);
        float4 o;
        o.x = (h1a + h2a + (a0 + b0)) * (1.0f / 3.0f);
        o.y = (h1b + h2b + (a1 + b1)) * (1.0f / 3.0f);
        o.z = (h1c + h2c + (a2 + b2)) * (1.0f / 3.0f);
        o.w = (h1d + h2d + (a3 + b3)) * (1.0f / 3.0f);
        *(float4*)(out + idx) = o;
        float4 l;
        l.x = h1a; l.y = h1b; l.z = h1c; l.w = h1d;
        *(float4*)(out + (size_t)n * D + idx) = l;
    }
}

// ---------------- launch ----------------

extern "C" void kernel_launch(void* const* d_in, const int* in_sizes, int n_in,
                              void* d_out, int out_size, void* d_ws, size_t ws_size,
                              hipStream_t stream) {
    const void* ue   = d_in[0];
    const void* ie   = d_in[1];
    const int*  row  = (const int*)d_in[2];
    const int*  col  = (const int*)d_in[3];
    const void* vals = d_in[4];

    const int nu  = in_sizes[0] / D;   // 100000
    const int ni  = in_sizes[1] / D;   //  50000
    const int n   = nu + ni;           // 150000
    const int nnz = in_sizes[2];       // 4800000

    // workspace (~97 MB). es2 aliases X1+X2 (dead before spmm writes X1).
    char* ws = (char*)d_ws;
    u16*  X0     = (u16*)ws;   ws += (size_t)n * D * sizeof(u16);
    u16*  X1     = (u16*)ws;   ws += (size_t)n * D * sizeof(u16);
    u16*  X2     = (u16*)ws;   ws += (size_t)n * D * sizeof(u16);
    int2* es2    = (int2*)X1;  // nnz*8B == 2*n*D*2B exactly
    int2* es     = (int2*)ws;  ws += (size_t)nnz * sizeof(int2);
    int*  rp     = (int*)ws;   ws += (size_t)(n + 1) * sizeof(int);
    int*  bcnt   = (int*)ws;   ws += NBP * sizeof(int);
    int*  flags  = (int*)ws;   ws += 2 * sizeof(int);
    int*  bbase  = (int*)ws;   ws += (NBP + 1) * sizeof(int);
    int*  bcursor= (int*)ws;   ws += NBP * sizeof(int);

    const int tb = 256;
    const int rblocks = (n + 15) / 16;             // 4 rows/wave, 4 waves/block
    const int cblocks = (n * D / 4 + tb - 1) / tb;
    const int NB      = (n + 511) / 512;            // 293
    const int coarseb = (nnz + TILE - 1) / TILE;    // 2344

    // zero bcnt + flags (contiguous)
    hipMemsetAsync(bcnt, 0, (NBP + 2) * sizeof(int), stream);
    detect_kernel <<<1, 64, 0, stream>>>((const u16*)ue, (const u16*)vals, flags);
    convert_kernel<<<cblocks, tb, 0, stream>>>(ue, ie, flags, X0, n * D, nu * D);
    bhist_kernel  <<<512, tb, 0, stream>>>(row, bcnt, nnz);
    bscan_kernel  <<<1, NBP, 0, stream>>>(bcnt, bbase, bcursor, NB, nnz);
    coarse_kernel <<<coarseb, tb, 0, stream>>>(row, col, vals, flags, bcursor, es2, nnz);
    fine_kernel   <<<NB, 512, 0, stream>>>(es2, bbase, es, rp, n, nnz);

    spmm_kernel     <<<rblocks, tb, 0, stream>>>(X0, X1, rp, es, n);
    spmm_kernel     <<<rblocks, tb, 0, stream>>>(X1, X2, rp, es, n);
    spmm_last_kernel<<<rblocks, tb, 0, stream>>>(X2, X1, (float*)d_out, rp, es, n);
}